// Round 1
// baseline (97.366 us; speedup 1.0000x reference)
//
#include <hip/hip_runtime.h>
#include <stdint.h>

// Problem constants (match reference)
#define Bdim 64
#define Tdim 1024
#define Edim 128
#define Cdim 5
#define Fdim 64
#define Hpad 2      // C/2

// LDS tile geometry
#define TTILE 128               // t-positions per workgroup
#define XROWS (TTILE + Cdim - 1) // 132 rows: t0-2 .. t0+129
#define LDSTR (Edim + 8)        // +8 bf16 pad -> 2-way bank alias only (free)

typedef __attribute__((ext_vector_type(8))) short short8;     // 8 bf16 = 4 VGPRs (MFMA frag)
typedef __attribute__((ext_vector_type(4))) float float4v;
typedef __attribute__((ext_vector_type(4))) unsigned short ushort4v;

__device__ __forceinline__ unsigned short f2bf(float f) {
    // round-to-nearest-even fp32 -> bf16 (inputs are finite randn; no NaN path needed)
    union { float f; uint32_t u; } v; v.f = f;
    uint32_t u = v.u;
    u += 0x7fffu + ((u >> 16) & 1u);
    return (unsigned short)(u >> 16);
}

__global__ __launch_bounds__(256, 2)
void qa_cnn_kernel(const float* __restrict__ x, const float* __restrict__ W,
                   const float* __restrict__ bias, float* __restrict__ out) {
    __shared__ __align__(16) unsigned short sX[XROWS * LDSTR]; // 35.9 KB
    __shared__ __align__(16) unsigned short sW[Fdim * LDSTR];  // 17.4 KB

    const int tid = threadIdx.x;
    const int tt  = blockIdx.x;   // t-tile index 0..7
    const int b   = blockIdx.y;   // batch
    const int t0  = tt * TTILE;

    // ---- Stage x window once: rows t0-2 .. t0+129, fp32 -> bf16, zero-pad edges
    {
        const int nslots = XROWS * (Edim / 4);          // float4 slots = 132*32
        for (int idx = tid; idx < nslots; idx += 256) {
            const int row = idx >> 5;                    // /32
            const int c4  = idx & 31;
            const int gt  = t0 - Hpad + row;
            float4v v = {0.f, 0.f, 0.f, 0.f};
            if (gt >= 0 && gt < Tdim) {
                v = *(const float4v*)(x + ((size_t)b * Tdim + gt) * Edim + c4 * 4);
            }
            ushort4v o = { f2bf(v.x), f2bf(v.y), f2bf(v.z), f2bf(v.w) };
            *(ushort4v*)&sX[row * LDSTR + c4 * 4] = o;
        }
    }

    const int wave = tid >> 6;     // 0..3 -> wave's 32-t slice
    const int lane = tid & 63;
    const int m16  = lane & 15;
    const int quad = lane >> 4;

    float4v acc[2][4];
    #pragma unroll
    for (int i = 0; i < 2; ++i)
        #pragma unroll
        for (int j = 0; j < 4; ++j) acc[i][j] = (float4v){0.f, 0.f, 0.f, 0.f};

    // ---- Tap loop: each tap c is a K=128 GEMM; A rows are just sX shifted by c
    for (int c = 0; c < Cdim; ++c) {
        __syncthreads();  // protect previous tap's sW reads (and first-iter sX writes)
        // stage W chunk c: W[f][c*128 + e] -> sW[f][e] (bf16)
        for (int idx = tid; idx < Fdim * (Edim / 4); idx += 256) {
            const int f  = idx >> 5;
            const int c4 = idx & 31;
            float4v v = *(const float4v*)(W + (size_t)f * (Cdim * Edim) + c * Edim + c4 * 4);
            ushort4v o = { f2bf(v.x), f2bf(v.y), f2bf(v.z), f2bf(v.w) };
            *(ushort4v*)&sW[f * LDSTR + c4 * 4] = o;
        }
        __syncthreads();

        #pragma unroll
        for (int kk = 0; kk < Edim; kk += 32) {
            const int kcol = kk + quad * 8;
            short8 afrag[2];
            #pragma unroll
            for (int mt = 0; mt < 2; ++mt) {
                const int row = c + wave * 32 + mt * 16 + m16;   // A[m][k], m=lane&15
                afrag[mt] = *(const short8*)&sX[row * LDSTR + kcol];
            }
            #pragma unroll
            for (int nt = 0; nt < 4; ++nt) {
                const short8 bfrag = *(const short8*)&sW[(nt * 16 + m16) * LDSTR + kcol]; // B[k][n], n=lane&15
                #pragma unroll
                for (int mt = 0; mt < 2; ++mt) {
                    acc[mt][nt] = __builtin_amdgcn_mfma_f32_16x16x32_bf16(
                        afrag[mt], bfrag, acc[mt][nt], 0, 0, 0);
                }
            }
        }
    }

    // ---- Epilogue: D layout col(n=f)=lane&15, row(m=t)=quad*4+reg -> 4 consecutive t per lane
    #pragma unroll
    for (int nt = 0; nt < 4; ++nt) {
        const int f  = nt * 16 + m16;
        const float bv = bias[f];
        #pragma unroll
        for (int mt = 0; mt < 2; ++mt) {
            const int t = t0 + wave * 32 + mt * 16 + quad * 4;
            float4v v = acc[mt][nt];
            v.x += bv; v.y += bv; v.z += bv; v.w += bv;
            *(float4v*)(out + ((size_t)b * Fdim + f) * Tdim + t) = v;
        }
    }
}

extern "C" void kernel_launch(void* const* d_in, const int* in_sizes, int n_in,
                              void* d_out, int out_size, void* d_ws, size_t ws_size,
                              hipStream_t stream) {
    const float* x    = (const float*)d_in[0];   // [B, T, E]
    const float* W    = (const float*)d_in[1];   // [F, C*E]
    const float* bias = (const float*)d_in[2];   // [F]
    float* out = (float*)d_out;                  // [B, F, T]

    dim3 grid(Tdim / TTILE, Bdim);  // (8, 64)
    dim3 block(256);
    qa_cnn_kernel<<<grid, block, 0, stream>>>(x, W, bias, out);
}

// Round 2
// 92.344 us; speedup vs baseline: 1.0544x; 1.0544x over previous
//
#include <hip/hip_runtime.h>
#include <stdint.h>

// Problem constants (match reference)
#define Bdim 64
#define Tdim 1024
#define Edim 128
#define Cdim 5
#define Fdim 64
#define Hpad 2      // C/2
#define Kdim (Cdim * Edim)   // 640

// Tile geometry
#define TTILE 64                 // t-positions per workgroup
#define XROWS (TTILE + Cdim - 1) // 68 rows: t0-2 .. t0+65
#define LDSTR (Edim + 8)         // 136 shorts/row; +8 pad -> only 2-way bank alias (free)

typedef __attribute__((ext_vector_type(8))) short short8;     // 8 bf16 = 4 VGPRs (MFMA frag)
typedef __attribute__((ext_vector_type(4))) float float4v;
typedef __attribute__((ext_vector_type(4))) unsigned short ushort4v;

__device__ __forceinline__ unsigned short f2bf(float f) {
    // round-to-nearest-even fp32 -> bf16 (inputs finite randn; no NaN path needed)
    union { float f; uint32_t u; } v; v.f = f;
    uint32_t u = v.u;
    u += 0x7fffu + ((u >> 16) & 1u);
    return (unsigned short)(u >> 16);
}

// ---- Pre-kernel: W fp32 [F, C*E] -> bf16, same row-major layout, into d_ws.
// 40960 elements = 10240 float4 slots.
__global__ void convert_W(const float* __restrict__ W, unsigned short* __restrict__ Wbf) {
    int i = blockIdx.x * 256 + threadIdx.x;
    if (i < (Fdim * Kdim) / 4) {
        float4v v = ((const float4v*)W)[i];
        ushort4v o = { f2bf(v.x), f2bf(v.y), f2bf(v.z), f2bf(v.w) };
        ((ushort4v*)Wbf)[i] = o;
    }
}

// ---- Main kernel: one block = 64 t-positions of one batch row; 4 waves split F.
// Single __syncthreads; B-fragments in registers (one tap at a time);
// A from LDS-staged bf16 x-window shifted by tap index.
__global__ __launch_bounds__(256, 4)
void qa_cnn_main(const float* __restrict__ x, const unsigned short* __restrict__ Wbf,
                 const float* __restrict__ bias, float* __restrict__ out) {
    __shared__ __align__(16) unsigned short sX[XROWS * LDSTR]; // 18,496 B

    const int tid = threadIdx.x;
    const int tt  = blockIdx.x;   // 0..15
    const int b   = blockIdx.y;   // 0..63
    const int t0  = tt * TTILE;

    // Stage x window: rows t0-2 .. t0+65, fp32 -> bf16, zero-pad T edges.
    {
        const int nslots = XROWS * (Edim / 4);  // 68*32 = 2176 float4 slots
        for (int idx = tid; idx < nslots; idx += 256) {
            const int row = idx >> 5;
            const int c4  = idx & 31;
            const int gt  = t0 - Hpad + row;
            float4v v = {0.f, 0.f, 0.f, 0.f};
            if (gt >= 0 && gt < Tdim) {
                v = *(const float4v*)(x + ((size_t)b * Tdim + gt) * Edim + c4 * 4);
            }
            ushort4v o = { f2bf(v.x), f2bf(v.y), f2bf(v.z), f2bf(v.w) };
            *(ushort4v*)&sX[row * LDSTR + c4 * 4] = o;
        }
    }
    __syncthreads();   // the only barrier

    const int wave = tid >> 6;     // 0..3 -> this wave's 16-f slice
    const int lane = tid & 63;
    const int m16  = lane & 15;
    const int quad = lane >> 4;

    // B-frag source: W[n = 16*wave + m16][k = c*128 + kk*32 + quad*8 + j]
    const unsigned short* wrow = Wbf + (size_t)(wave * 16 + m16) * Kdim + quad * 8;

    float4v acc[4];
    #pragma unroll
    for (int mt = 0; mt < 4; ++mt) acc[mt] = (float4v){0.f, 0.f, 0.f, 0.f};

    #pragma unroll
    for (int c = 0; c < Cdim; ++c) {
        short8 bfrag[4];
        #pragma unroll
        for (int kk = 0; kk < 4; ++kk)
            bfrag[kk] = *(const short8*)(wrow + c * Edim + kk * 32);

        #pragma unroll
        for (int kk = 0; kk < 4; ++kk) {
            const int kcol = kk * 32 + quad * 8;
            #pragma unroll
            for (int mt = 0; mt < 4; ++mt) {
                // A[m = m16][k], row in sX shifted by tap c
                const short8 a = *(const short8*)&sX[(c + mt * 16 + m16) * LDSTR + kcol];
                acc[mt] = __builtin_amdgcn_mfma_f32_16x16x32_bf16(a, bfrag[kk], acc[mt], 0, 0, 0);
            }
        }
    }

    // Epilogue: D col(n)=lane&15 -> f, row(m)=quad*4+reg -> t. 4 consecutive t/lane.
    const int f  = wave * 16 + m16;
    const float bv = bias[f];
    float* orow = out + ((size_t)b * Fdim + f) * Tdim + t0 + quad * 4;
    #pragma unroll
    for (int mt = 0; mt < 4; ++mt) {
        float4v v = acc[mt];
        v.x += bv; v.y += bv; v.z += bv; v.w += bv;
        *(float4v*)(orow + mt * 16) = v;
    }
}

extern "C" void kernel_launch(void* const* d_in, const int* in_sizes, int n_in,
                              void* d_out, int out_size, void* d_ws, size_t ws_size,
                              hipStream_t stream) {
    const float* x    = (const float*)d_in[0];   // [B, T, E]
    const float* W    = (const float*)d_in[1];   // [F, C*E]
    const float* bias = (const float*)d_in[2];   // [F]
    float* out = (float*)d_out;                  // [B, F, T]
    unsigned short* Wbf = (unsigned short*)d_ws; // 80 KB bf16 copy of W

    convert_W<<<dim3((Fdim * Kdim / 4 + 255) / 256), dim3(256), 0, stream>>>(W, Wbf);
    qa_cnn_main<<<dim3(Tdim / TTILE, Bdim), dim3(256), 0, stream>>>(x, Wbf, bias, out);
}